// Round 10
// baseline (1474.073 us; speedup 1.0000x reference)
//
#include <hip/hip_runtime.h>

// LSTM_77893526880768: B=T=F=H=256.  256 independent row-chains, 255 steps.
//
// v10 = v9 with flag contention removed. R9 proved the same-XCD fast path
// engaged (WRITE_SIZE 34MB -> 1.3MB: no more per-step wbl2 of h) but step
// time only fell to 4.8us. Residual theory: ALL 64 WGs' polls + 64 RMWs hit
// ONE 64-B IC line (flags[t*8+rg], rg 0..7 contiguous) => per-line IC
// serialization queues thousands of cycles onto the critical path each step.
// v10: (1) per-rg flag block at 256-B stride (own line: 16 accessors, not
// 128); (2) store-based monotonic flags (v2-proven): producer POSTS value
// t+1 to its own slot (no RMW round-trip); consumer polls 8 slots via 4x8B
// packed relaxed loads. Fast-path ordering unchanged (barrier vmcnt drain ->
// flag store). Slow path keeps v7's RELEASE/acquire.
//
//   64 WGs = 8 rg x 8 cg, 256 threads.  LDS: 4g x 32c x 256k bf16 = 64 KB
//   weights (v5-verified layout).  All 4 gates per lane via shfl_xor(8).
//   c in fp32 regs.  t=0 skips the h read (h_0 = 0).
//
// Workspace layout:
//   [0, 2K)         flags int[8][64] (256-B stride per rg; memset 0)
//   [8K, 8K+256)    xcd_tab int[64]
//   [16K, 16K+256K) Hbuf bf16[2][256][256] (uninit; never read before write)
//   [0, 512K)       WxT bf16   (live only until precompute finishes)
//   [512K, 1M)      WhT bf16
//   [1M, 1M+4K)     bcat fp32
//   [1M+4K, ...)    P bf16  [t][rg16][n][16] = 133,693,440 B

#define STEPS 255

typedef short bf16x8 __attribute__((ext_vector_type(8)));
typedef short bf16x4 __attribute__((ext_vector_type(4)));
typedef float f32x4  __attribute__((ext_vector_type(4)));

__device__ inline unsigned short f2bf(float f) {
  unsigned int u = __float_as_uint(f);
  unsigned int r = (u + 0x7FFFu + ((u >> 16) & 1u)) >> 16;  // RNE
  return (unsigned short)r;
}
__device__ inline float bf2f(unsigned short s) {
  return __uint_as_float(((unsigned int)s) << 16);
}
__device__ inline float sig_f(float x) {
  float e = exp2f(-1.442695041f * x);
  return __builtin_amdgcn_rcpf(1.0f + e);
}
__device__ inline float tanh_f(float x) {
  float e = exp2f(-2.885390082f * x);
  return 2.0f * __builtin_amdgcn_rcpf(1.0f + e) - 1.0f;
}

// ---------- prep: W transpose (W[k][j] fp32 -> WT[g*256+j][k] bf16) ----------
__global__ __launch_bounds__(256) void lstm_prep_w(
    const float* __restrict__ m0, const float* __restrict__ m1,
    const float* __restrict__ m2, const float* __restrict__ m3,
    const float* __restrict__ m4, const float* __restrict__ m5,
    const float* __restrict__ m6, const float* __restrict__ m7,
    unsigned short* __restrict__ WxT, unsigned short* __restrict__ WhT) {
  const float* mats[8] = {m0, m1, m2, m3, m4, m5, m6, m7};
  int mat = blockIdx.z;
  const float* W = mats[mat];
  unsigned short* out = (mat < 4 ? WxT : WhT) + (size_t)(mat & 3) * 256 * 256;
  int kblk = blockIdx.x * 32, jblk = blockIdx.y * 32;
  __shared__ float tile[32][33];
  int tx = threadIdx.x & 31, ty = threadIdx.x >> 5;
#pragma unroll
  for (int i = 0; i < 4; ++i) {
    int kk = ty + i * 8;
    tile[kk][tx] = W[(size_t)(kblk + kk) * 256 + jblk + tx];
  }
  __syncthreads();
#pragma unroll
  for (int i = 0; i < 4; ++i) {
    int jj = ty + i * 8;
    out[(size_t)(jblk + jj) * 256 + kblk + tx] = f2bf(tile[tx][jj]);
  }
}

// ---------- prep: bias fold ----------
__global__ void lstm_prep_b(
    const float* __restrict__ bx0, const float* __restrict__ bx1,
    const float* __restrict__ bx2, const float* __restrict__ bx3,
    const float* __restrict__ bh0, const float* __restrict__ bh1,
    const float* __restrict__ bh2, const float* __restrict__ bh3,
    float* __restrict__ bcat) {
  const float* bx[4] = {bx0, bx1, bx2, bx3};
  const float* bh[4] = {bh0, bh1, bh2, bh3};
  int i = blockIdx.x * 256 + threadIdx.x;
  int g = i >> 8, j = i & 255;
  bcat[i] = bx[g][j] + bh[g][j];
}

// ---------- precompute: P[t][rg16][n][rl] = bcat[n] + sum_k x[r,t,k] Wx[k,n] ----------
// grid (255, 2): blockIdx.y selects 8 of the 16 n-blocks (x-frags duplicated).
__global__ __launch_bounds__(256, 1) void lstm_precompute(
    const float* __restrict__ x, const unsigned short* __restrict__ WxT,
    const float* __restrict__ bcat, unsigned short* __restrict__ P) {
  int t = blockIdx.x;
  int tid = threadIdx.x;
  int w = tid >> 6, lane = tid & 63, q = lane >> 4, cl = lane & 15;
  int rbase = w * 64;

  bf16x8 bfrag[8][4];
#pragma unroll
  for (int kt = 0; kt < 8; ++kt) {
    int k0 = kt * 32 + q * 8;
#pragma unroll
    for (int rt = 0; rt < 4; ++rt) {
      const float* xp = x + (((size_t)(rbase + rt * 16 + cl) * 256 + t) * 256 + k0);
      f32x4 lo = *(const f32x4*)xp;
      f32x4 hi = *(const f32x4*)(xp + 4);
      bf16x8 bv;
      bv[0] = (short)f2bf(lo[0]); bv[1] = (short)f2bf(lo[1]);
      bv[2] = (short)f2bf(lo[2]); bv[3] = (short)f2bf(lo[3]);
      bv[4] = (short)f2bf(hi[0]); bv[5] = (short)f2bf(hi[1]);
      bv[6] = (short)f2bf(hi[2]); bv[7] = (short)f2bf(hi[3]);
      bfrag[kt][rt] = bv;
    }
  }

  for (int nbi = 0; nbi < 8; ++nbi) {
    int nblk = (blockIdx.y * 8 + nbi) * 64;
    f32x4 acc[4][4];
#pragma unroll
    for (int a = 0; a < 4; ++a)
#pragma unroll
      for (int b = 0; b < 4; ++b) acc[a][b] = f32x4{0.f, 0.f, 0.f, 0.f};

#pragma unroll
    for (int kt = 0; kt < 8; ++kt) {
      int k0 = kt * 32 + q * 8;
      bf16x8 afrag[4];
#pragma unroll
      for (int mt = 0; mt < 4; ++mt)
        afrag[mt] = *(const bf16x8*)(WxT + (size_t)(nblk + mt * 16 + cl) * 256 + k0);
#pragma unroll
      for (int mt = 0; mt < 4; ++mt)
#pragma unroll
        for (int rt = 0; rt < 4; ++rt)
          acc[mt][rt] = __builtin_amdgcn_mfma_f32_16x16x32_bf16(
              afrag[mt], bfrag[kt][rt], acc[mt][rt], 0, 0, 0);
    }
#pragma unroll
    for (int mt = 0; mt < 4; ++mt) {
#pragma unroll
      for (int reg = 0; reg < 4; ++reg) {
        int n = nblk + mt * 16 + q * 4 + reg;
        float bb = bcat[n];
#pragma unroll
        for (int rt = 0; rt < 4; ++rt) {
          int rg16 = w * 4 + rt;  // = r>>4
          P[(((size_t)t * 16 + rg16) * 1024 + n) * 16 + cl] = f2bf(acc[mt][rt][reg] + bb);
        }
      }
    }
  }
}

// ---------- recurrent v10: padded store-based flags ----------
__global__ __launch_bounds__(256, 1) void lstm_recurrent(
    const unsigned short* __restrict__ WhT,
    const unsigned short* __restrict__ P,
    unsigned short* Hbuf, int* flags, int* xcd_tab,
    float* __restrict__ out) {
  // Weight fragments, MFMA B-layout, exactly 64 KB (v5-verified):
  __shared__ bf16x8 wlds[4][2][8][64];

  int tid = threadIdx.x;
  int w = tid >> 6, lane = tid & 63, q = lane >> 4, cl = lane & 15;
  int rg = blockIdx.x;  // rows [rg*32, rg*32+32)
  int cg = blockIdx.y;  // cols [cg*32, cg*32+32)
  int r0 = rg * 32;
  int jglob = cg * 32 + w * 8 + (cl & 7);
  int* frg = flags + rg * 64;  // this rg's 256-B flag block (8 cg slots)

  // ---- one-time XCD exchange (proven release/acquire; before weights stage)
  int* same_lds = (int*)&wlds[0][0][0][0];
  if (tid == 0) {
    unsigned xcc;
    asm volatile("s_getreg_b32 %0, hwreg(HW_REG_XCC_ID)" : "=s"(xcc));
    __hip_atomic_store(&xcd_tab[rg * 8 + cg], (int)xcc + 1,
                       __ATOMIC_RELEASE, __HIP_MEMORY_SCOPE_SYSTEM);
    int v0 = 0, samev = 1;
    for (int j = 0; j < 8; ++j) {
      int v;
      while ((v = __hip_atomic_load(&xcd_tab[rg * 8 + j],
                                    __ATOMIC_ACQUIRE, __HIP_MEMORY_SCOPE_SYSTEM)) == 0)
        __builtin_amdgcn_s_sleep(1);
      if (j == 0) v0 = v;
      else if (v != v0) samev = 0;
    }
    same_lds[0] = samev;
  }
  __syncthreads();
  int same = same_lds[0];
  __syncthreads();

  // ---- stage weights into LDS (once): 4096 16B-chunks, 16 per thread
  for (int i = 0; i < 16; ++i) {
    int idx = tid + i * 256;
    int sw = idx >> 10, snt = (idx >> 9) & 1, skt = (idx >> 6) & 7, sl = idx & 63;
    int sq = sl >> 4, scl = sl & 15;
    int gate = snt * 2 + (scl >> 3);
    int col = cg * 32 + sw * 8 + (scl & 7);
    int k0 = skt * 32 + sq * 8;
    (&wlds[0][0][0][0])[idx] = *(const bf16x8*)(WhT + (size_t)(gate * 256 + col) * 256 + k0);
  }
  __syncthreads();

  float creg[2][4] = {{0.f, 0.f, 0.f, 0.f}, {0.f, 0.f, 0.f, 0.f}};
  unsigned short* H0 = Hbuf;             // [256][256] bf16 (uninit; t=0 skips read)
  unsigned short* H1 = Hbuf + 65536;

  for (int t = 0; t < STEPS; ++t) {
    // P prefetch (independent of peers) before the flag wait — lands in regs.
    bf16x4 pv[2][4];
#pragma unroll
    for (int rt = 0; rt < 2; ++rt) {
      int rg16 = rg * 2 + rt;
#pragma unroll
      for (int g = 0; g < 4; ++g)
        pv[rt][g] = *(const bf16x4*)(
            P + (((size_t)t * 16 + rg16) * 1024 + g * 256 + jglob) * 16 + q * 4);
    }

    bf16x8 afrag[2][8];
    if (t > 0) {
      if (tid == 0) {
        // poll all 8 cg slots (monotonic values; done when all >= t) with
        // packed 8B relaxed loads — one padded line, 16 accessors total.
        const unsigned long long* f64 = (const unsigned long long*)frg;
        for (;;) {
          unsigned long long a = __hip_atomic_load(f64 + 0, __ATOMIC_RELAXED, __HIP_MEMORY_SCOPE_SYSTEM);
          unsigned long long b = __hip_atomic_load(f64 + 1, __ATOMIC_RELAXED, __HIP_MEMORY_SCOPE_SYSTEM);
          unsigned long long c = __hip_atomic_load(f64 + 2, __ATOMIC_RELAXED, __HIP_MEMORY_SCOPE_SYSTEM);
          unsigned long long d = __hip_atomic_load(f64 + 3, __ATOMIC_RELAXED, __HIP_MEMORY_SCOPE_SYSTEM);
          if ((int)a >= t && (int)(a >> 32) >= t && (int)b >= t && (int)(b >> 32) >= t &&
              (int)c >= t && (int)(c >> 32) >= t && (int)d >= t && (int)(d >> 32) >= t)
            break;
          __builtin_amdgcn_s_sleep(1);
        }
        if (!same)  // v7 slow path: one cache-wide acquire inv (cross-XCD peers)
          __builtin_amdgcn_fence(__ATOMIC_ACQUIRE, "");
      }
      __syncthreads();

      const unsigned short* Hb = (t & 1) ? H1 : H0;
      if (same) {
        // FAST: peers share this XCD's L2; volatile (sc0) loads bypass L1 and
        // probe the shared L2 where peers' plain stores are ack'd. No inv.
        const volatile bf16x8* Hv = (const volatile bf16x8*)Hb;
#pragma unroll
        for (int rt = 0; rt < 2; ++rt)
#pragma unroll
          for (int kt = 0; kt < 8; ++kt)
            afrag[rt][kt] = Hv[((size_t)(r0 + rt * 16 + cl) * 256 + kt * 32 + q * 8) >> 3];
      } else {
        // SLOW (v7-proven): plain loads post-inv.
#pragma unroll
        for (int rt = 0; rt < 2; ++rt)
#pragma unroll
          for (int kt = 0; kt < 8; ++kt)
            afrag[rt][kt] = *(const bf16x8*)(Hb + (size_t)(r0 + rt * 16 + cl) * 256 + kt * 32 + q * 8);
      }
    } else {
      // t = 0: h_0 = 0 -> no read, no wait (Hbuf may be uninitialized).
#pragma unroll
      for (int rt = 0; rt < 2; ++rt)
#pragma unroll
        for (int kt = 0; kt < 8; ++kt)
          afrag[rt][kt] = (bf16x8){0, 0, 0, 0, 0, 0, 0, 0};
    }

    // ---- MFMA: 2 row-tiles x 2 n-tiles ({i,f},{g,o} x 8 cols) x 8 k-tiles
    f32x4 acc[2][2];
#pragma unroll
    for (int rt = 0; rt < 2; ++rt)
#pragma unroll
      for (int nt = 0; nt < 2; ++nt) acc[rt][nt] = f32x4{0.f, 0.f, 0.f, 0.f};
#pragma unroll
    for (int kt = 0; kt < 8; ++kt)
#pragma unroll
      for (int rt = 0; rt < 2; ++rt)
#pragma unroll
        for (int nt = 0; nt < 2; ++nt)
          acc[rt][nt] = __builtin_amdgcn_mfma_f32_16x16x32_bf16(
              afrag[rt][kt], wlds[w][nt][kt][lane], acc[rt][nt], 0, 0, 0);

    // ---- elementwise: lane cl holds (cl<8 ? {i,g} : {f,o}); shfl_xor(8) pairs.
    unsigned short* Hw = ((t & 1) ? H0 : H1);
    bool last = (t == STEPS - 1);
    bool lo = (cl & 8) == 0;
#pragma unroll
    for (int rt = 0; rt < 2; ++rt) {
#pragma unroll
      for (int e = 0; e < 4; ++e) {
        float own0 = acc[rt][0][e], oth0 = __shfl_xor(own0, 8, 64);
        float own1 = acc[rt][1][e], oth1 = __shfl_xor(own1, 8, 64);
        float pi = (lo ? own0 : oth0) + bf2f((unsigned short)pv[rt][0][e]);
        float pf = (lo ? oth0 : own0) + bf2f((unsigned short)pv[rt][1][e]);
        float pg = (lo ? own1 : oth1) + bf2f((unsigned short)pv[rt][2][e]);
        float po = (lo ? oth1 : own1) + bf2f((unsigned short)pv[rt][3][e]);
        float ig = sig_f(pi), fg = sig_f(pf), gg = tanh_f(pg), og = sig_f(po);
        float cn = fg * creg[rt][e] + ig * gg;
        creg[rt][e] = cn;
        float hn = og * tanh_f(cn);
        int r = r0 + rt * 16 + q * 4 + e;
        if (lo) {
          if (!last) {
            Hw[(size_t)r * 256 + jglob] = f2bf(hn);  // plain store -> shared L2
          } else {
            out[(size_t)r * 256 + jglob] = hn;
            out[65536 + (size_t)r * 256 + jglob] = cn;
          }
        }
      }
    }

    if (!last) {
      // All waves' h stores are vmcnt-drained into L2 by this barrier.
      __syncthreads();
      if (tid == 0) {
        if (same)
          // FAST: posted store (no RMW round-trip); h already visible in the
          // shared L2 to peers' volatile loads when the flag lands at the IC.
          __hip_atomic_store(frg + cg, t + 1,
                             __ATOMIC_RELAXED, __HIP_MEMORY_SCOPE_SYSTEM);
        else
          // SLOW (v7-proven): RELEASE = wbl2 publishes L2-dirty h to IC first
          __hip_atomic_store(frg + cg, t + 1,
                             __ATOMIC_RELEASE, __HIP_MEMORY_SCOPE_SYSTEM);
      }
    }
  }
}

extern "C" void kernel_launch(void* const* d_in, const int* in_sizes, int n_in,
                              void* d_out, int out_size, void* d_ws, size_t ws_size,
                              hipStream_t stream) {
  const float* x = (const float*)d_in[0];
  const float* wx0 = (const float*)d_in[1];
  const float* wx1 = (const float*)d_in[5];
  const float* wx2 = (const float*)d_in[9];
  const float* wx3 = (const float*)d_in[13];
  const float* wh0 = (const float*)d_in[3];
  const float* wh1 = (const float*)d_in[7];
  const float* wh2 = (const float*)d_in[11];
  const float* wh3 = (const float*)d_in[15];
  const float* bx0 = (const float*)d_in[2];
  const float* bx1 = (const float*)d_in[6];
  const float* bx2 = (const float*)d_in[10];
  const float* bx3 = (const float*)d_in[14];
  const float* bh0 = (const float*)d_in[4];
  const float* bh1 = (const float*)d_in[8];
  const float* bh2 = (const float*)d_in[12];
  const float* bh3 = (const float*)d_in[16];

  char* ws = (char*)d_ws;
  unsigned short* WxT = (unsigned short*)(ws + 0);          // dead after precompute
  unsigned short* WhT = (unsigned short*)(ws + 524288);
  float* bcat = (float*)(ws + 1048576);
  unsigned short* P = (unsigned short*)(ws + 1052672);      // [t][rg16][n][16] bf16
  int* flags = (int*)(ws + 0);                              // int[8][64], 256-B/rg
  int* xcd_tab = (int*)(ws + 8192);                         // 64 ints
  unsigned short* Hbuf = (unsigned short*)(ws + 16384);     // [2][256][256] bf16

  lstm_prep_w<<<dim3(8, 8, 8), 256, 0, stream>>>(wx0, wx1, wx2, wx3,
                                                 wh0, wh1, wh2, wh3, WxT, WhT);
  lstm_prep_b<<<4, 256, 0, stream>>>(bx0, bx1, bx2, bx3, bh0, bh1, bh2, bh3, bcat);
  lstm_precompute<<<dim3(255, 2), 256, 0, stream>>>(x, WxT, bcat, P);
  hipMemsetAsync(ws, 0, 16384, stream);  // flags + xcd_tab (Hbuf never pre-read)
  lstm_recurrent<<<dim3(8, 8), 256, 0, stream>>>(WhT, P, Hbuf, flags, xcd_tab,
                                                 (float*)d_out);
}

// Round 11
// 1463.226 us; speedup vs baseline: 1.0074x; 1.0074x over previous
//
#include <hip/hip_runtime.h>

// LSTM_77893526880768: B=T=F=H=256.  256 independent row-chains, 255 steps.
//
// v11 = v10 with the fast-path handshake moved from SYSTEM scope (Infinity
// Cache) down to AGENT scope (the shared XCD L2).
//
// R10 accounting: per step ~3.2k cyc compute issue vs ~8.4k cyc wait; flag
// padding + posted stores were NEUTRAL => the wait is the IC round trip of
// the system-scope flag ops themselves (publish ~1k + detect ~1.4k), paid
// twice per step. With cg-peers runtime-VERIFIED on one XCD (v9), the L2 is
// the common coherence point: agent-relaxed store = write-through to L2;
// agent-relaxed load = glc (L1-bypass) read of the same L2. h stores and the
// flag store drain into the SAME L2 (barrier vmcnt(0) orders them) — no
// cross-cache channel race (v6/v8's failure mode needed two caches).
// h reads stay volatile sc0 L2 probes (v9-proven). Slow path = v7 verbatim.
//
//   64 WGs = 8 rg x 8 cg (grid (8,8): %8 round-robin pins cg-peers per XCD).
//   LDS: 4g x 32c x 256k bf16 = 64 KB weights (v5-verified layout).
//   All 4 gates per lane via shfl_xor(8); c in fp32 regs; t=0 skips h read.
//
// Workspace layout:
//   [0, 2K)         flags int[8][64] (256-B stride per rg; memset 0)
//   [8K, 8K+256)    xcd_tab int[64]
//   [16K, 16K+256K) Hbuf bf16[2][256][256] (uninit; never read before write)
//   [0, 512K)       WxT bf16   (live only until precompute finishes)
//   [512K, 1M)      WhT bf16
//   [1M, 1M+4K)     bcat fp32
//   [1M+4K, ...)    P bf16  [t][rg16][n][16] = 133,693,440 B

#define STEPS 255

typedef short bf16x8 __attribute__((ext_vector_type(8)));
typedef short bf16x4 __attribute__((ext_vector_type(4)));
typedef float f32x4  __attribute__((ext_vector_type(4)));

__device__ inline unsigned short f2bf(float f) {
  unsigned int u = __float_as_uint(f);
  unsigned int r = (u + 0x7FFFu + ((u >> 16) & 1u)) >> 16;  // RNE
  return (unsigned short)r;
}
__device__ inline float bf2f(unsigned short s) {
  return __uint_as_float(((unsigned int)s) << 16);
}
__device__ inline float sig_f(float x) {
  float e = exp2f(-1.442695041f * x);
  return __builtin_amdgcn_rcpf(1.0f + e);
}
__device__ inline float tanh_f(float x) {
  float e = exp2f(-2.885390082f * x);
  return 2.0f * __builtin_amdgcn_rcpf(1.0f + e) - 1.0f;
}

// ---------- prep: W transpose (W[k][j] fp32 -> WT[g*256+j][k] bf16) ----------
__global__ __launch_bounds__(256) void lstm_prep_w(
    const float* __restrict__ m0, const float* __restrict__ m1,
    const float* __restrict__ m2, const float* __restrict__ m3,
    const float* __restrict__ m4, const float* __restrict__ m5,
    const float* __restrict__ m6, const float* __restrict__ m7,
    unsigned short* __restrict__ WxT, unsigned short* __restrict__ WhT) {
  const float* mats[8] = {m0, m1, m2, m3, m4, m5, m6, m7};
  int mat = blockIdx.z;
  const float* W = mats[mat];
  unsigned short* out = (mat < 4 ? WxT : WhT) + (size_t)(mat & 3) * 256 * 256;
  int kblk = blockIdx.x * 32, jblk = blockIdx.y * 32;
  __shared__ float tile[32][33];
  int tx = threadIdx.x & 31, ty = threadIdx.x >> 5;
#pragma unroll
  for (int i = 0; i < 4; ++i) {
    int kk = ty + i * 8;
    tile[kk][tx] = W[(size_t)(kblk + kk) * 256 + jblk + tx];
  }
  __syncthreads();
#pragma unroll
  for (int i = 0; i < 4; ++i) {
    int jj = ty + i * 8;
    out[(size_t)(jblk + jj) * 256 + kblk + tx] = f2bf(tile[tx][jj]);
  }
}

// ---------- prep: bias fold ----------
__global__ void lstm_prep_b(
    const float* __restrict__ bx0, const float* __restrict__ bx1,
    const float* __restrict__ bx2, const float* __restrict__ bx3,
    const float* __restrict__ bh0, const float* __restrict__ bh1,
    const float* __restrict__ bh2, const float* __restrict__ bh3,
    float* __restrict__ bcat) {
  const float* bx[4] = {bx0, bx1, bx2, bx3};
  const float* bh[4] = {bh0, bh1, bh2, bh3};
  int i = blockIdx.x * 256 + threadIdx.x;
  int g = i >> 8, j = i & 255;
  bcat[i] = bx[g][j] + bh[g][j];
}

// ---------- precompute: P[t][rg16][n][rl] = bcat[n] + sum_k x[r,t,k] Wx[k,n] ----------
// grid (255, 2): blockIdx.y selects 8 of the 16 n-blocks (x-frags duplicated).
__global__ __launch_bounds__(256, 1) void lstm_precompute(
    const float* __restrict__ x, const unsigned short* __restrict__ WxT,
    const float* __restrict__ bcat, unsigned short* __restrict__ P) {
  int t = blockIdx.x;
  int tid = threadIdx.x;
  int w = tid >> 6, lane = tid & 63, q = lane >> 4, cl = lane & 15;
  int rbase = w * 64;

  bf16x8 bfrag[8][4];
#pragma unroll
  for (int kt = 0; kt < 8; ++kt) {
    int k0 = kt * 32 + q * 8;
#pragma unroll
    for (int rt = 0; rt < 4; ++rt) {
      const float* xp = x + (((size_t)(rbase + rt * 16 + cl) * 256 + t) * 256 + k0);
      f32x4 lo = *(const f32x4*)xp;
      f32x4 hi = *(const f32x4*)(xp + 4);
      bf16x8 bv;
      bv[0] = (short)f2bf(lo[0]); bv[1] = (short)f2bf(lo[1]);
      bv[2] = (short)f2bf(lo[2]); bv[3] = (short)f2bf(lo[3]);
      bv[4] = (short)f2bf(hi[0]); bv[5] = (short)f2bf(hi[1]);
      bv[6] = (short)f2bf(hi[2]); bv[7] = (short)f2bf(hi[3]);
      bfrag[kt][rt] = bv;
    }
  }

  for (int nbi = 0; nbi < 8; ++nbi) {
    int nblk = (blockIdx.y * 8 + nbi) * 64;
    f32x4 acc[4][4];
#pragma unroll
    for (int a = 0; a < 4; ++a)
#pragma unroll
      for (int b = 0; b < 4; ++b) acc[a][b] = f32x4{0.f, 0.f, 0.f, 0.f};

#pragma unroll
    for (int kt = 0; kt < 8; ++kt) {
      int k0 = kt * 32 + q * 8;
      bf16x8 afrag[4];
#pragma unroll
      for (int mt = 0; mt < 4; ++mt)
        afrag[mt] = *(const bf16x8*)(WxT + (size_t)(nblk + mt * 16 + cl) * 256 + k0);
#pragma unroll
      for (int mt = 0; mt < 4; ++mt)
#pragma unroll
        for (int rt = 0; rt < 4; ++rt)
          acc[mt][rt] = __builtin_amdgcn_mfma_f32_16x16x32_bf16(
              afrag[mt], bfrag[kt][rt], acc[mt][rt], 0, 0, 0);
    }
#pragma unroll
    for (int mt = 0; mt < 4; ++mt) {
#pragma unroll
      for (int reg = 0; reg < 4; ++reg) {
        int n = nblk + mt * 16 + q * 4 + reg;
        float bb = bcat[n];
#pragma unroll
        for (int rt = 0; rt < 4; ++rt) {
          int rg16 = w * 4 + rt;  // = r>>4
          P[(((size_t)t * 16 + rg16) * 1024 + n) * 16 + cl] = f2bf(acc[mt][rt][reg] + bb);
        }
      }
    }
  }
}

// ---------- recurrent v11: agent-scope (L2-level) fast-path handshake ----------
__global__ __launch_bounds__(256, 1) void lstm_recurrent(
    const unsigned short* __restrict__ WhT,
    const unsigned short* __restrict__ P,
    unsigned short* Hbuf, int* flags, int* xcd_tab,
    float* __restrict__ out) {
  // Weight fragments, MFMA B-layout, exactly 64 KB (v5-verified):
  __shared__ bf16x8 wlds[4][2][8][64];

  int tid = threadIdx.x;
  int w = tid >> 6, lane = tid & 63, q = lane >> 4, cl = lane & 15;
  int rg = blockIdx.x;  // rows [rg*32, rg*32+32)
  int cg = blockIdx.y;  // cols [cg*32, cg*32+32)
  int r0 = rg * 32;
  int jglob = cg * 32 + w * 8 + (cl & 7);
  int* frg = flags + rg * 64;  // this rg's 256-B flag block (8 cg slots)

  // ---- one-time XCD exchange (proven release/acquire; before weights stage)
  int* same_lds = (int*)&wlds[0][0][0][0];
  if (tid == 0) {
    unsigned xcc;
    asm volatile("s_getreg_b32 %0, hwreg(HW_REG_XCC_ID)" : "=s"(xcc));
    __hip_atomic_store(&xcd_tab[rg * 8 + cg], (int)xcc + 1,
                       __ATOMIC_RELEASE, __HIP_MEMORY_SCOPE_SYSTEM);
    int v0 = 0, samev = 1;
    for (int j = 0; j < 8; ++j) {
      int v;
      while ((v = __hip_atomic_load(&xcd_tab[rg * 8 + j],
                                    __ATOMIC_ACQUIRE, __HIP_MEMORY_SCOPE_SYSTEM)) == 0)
        __builtin_amdgcn_s_sleep(1);
      if (j == 0) v0 = v;
      else if (v != v0) samev = 0;
    }
    same_lds[0] = samev;
  }
  __syncthreads();
  int same = same_lds[0];
  __syncthreads();

  // ---- stage weights into LDS (once): 4096 16B-chunks, 16 per thread
  for (int i = 0; i < 16; ++i) {
    int idx = tid + i * 256;
    int sw = idx >> 10, snt = (idx >> 9) & 1, skt = (idx >> 6) & 7, sl = idx & 63;
    int sq = sl >> 4, scl = sl & 15;
    int gate = snt * 2 + (scl >> 3);
    int col = cg * 32 + sw * 8 + (scl & 7);
    int k0 = skt * 32 + sq * 8;
    (&wlds[0][0][0][0])[idx] = *(const bf16x8*)(WhT + (size_t)(gate * 256 + col) * 256 + k0);
  }
  __syncthreads();

  float creg[2][4] = {{0.f, 0.f, 0.f, 0.f}, {0.f, 0.f, 0.f, 0.f}};
  unsigned short* H0 = Hbuf;             // [256][256] bf16 (uninit; t=0 skips read)
  unsigned short* H1 = Hbuf + 65536;

  for (int t = 0; t < STEPS; ++t) {
    // P prefetch (independent of peers) before the flag wait — lands in regs.
    bf16x4 pv[2][4];
#pragma unroll
    for (int rt = 0; rt < 2; ++rt) {
      int rg16 = rg * 2 + rt;
#pragma unroll
      for (int g = 0; g < 4; ++g)
        pv[rt][g] = *(const bf16x4*)(
            P + (((size_t)t * 16 + rg16) * 1024 + g * 256 + jglob) * 16 + q * 4);
    }

    bf16x8 afrag[2][8];
    if (t > 0) {
      if (tid == 0) {
        const unsigned long long* f64 = (const unsigned long long*)frg;
        if (same) {
          // FAST: agent-relaxed loads = glc reads of the shared XCD L2 where
          // peers' flag stores are write-through committed. Tight poll (~L2
          // RT per iter), no sleep, no cache-wide ops.
          for (;;) {
            unsigned long long a = __hip_atomic_load(f64 + 0, __ATOMIC_RELAXED, __HIP_MEMORY_SCOPE_AGENT);
            unsigned long long b = __hip_atomic_load(f64 + 1, __ATOMIC_RELAXED, __HIP_MEMORY_SCOPE_AGENT);
            unsigned long long c = __hip_atomic_load(f64 + 2, __ATOMIC_RELAXED, __HIP_MEMORY_SCOPE_AGENT);
            unsigned long long d = __hip_atomic_load(f64 + 3, __ATOMIC_RELAXED, __HIP_MEMORY_SCOPE_AGENT);
            if ((int)a >= t && (int)(a >> 32) >= t && (int)b >= t && (int)(b >> 32) >= t &&
                (int)c >= t && (int)(c >> 32) >= t && (int)d >= t && (int)(d >> 32) >= t)
              break;
          }
        } else {
          // SLOW (v7-proven): system poll + one acquire inv.
          for (;;) {
            unsigned long long a = __hip_atomic_load(f64 + 0, __ATOMIC_RELAXED, __HIP_MEMORY_SCOPE_SYSTEM);
            unsigned long long b = __hip_atomic_load(f64 + 1, __ATOMIC_RELAXED, __HIP_MEMORY_SCOPE_SYSTEM);
            unsigned long long c = __hip_atomic_load(f64 + 2, __ATOMIC_RELAXED, __HIP_MEMORY_SCOPE_SYSTEM);
            unsigned long long d = __hip_atomic_load(f64 + 3, __ATOMIC_RELAXED, __HIP_MEMORY_SCOPE_SYSTEM);
            if ((int)a >= t && (int)(a >> 32) >= t && (int)b >= t && (int)(b >> 32) >= t &&
                (int)c >= t && (int)(c >> 32) >= t && (int)d >= t && (int)(d >> 32) >= t)
              break;
            __builtin_amdgcn_s_sleep(1);
          }
          __builtin_amdgcn_fence(__ATOMIC_ACQUIRE, "");
        }
      }
      __syncthreads();

      const unsigned short* Hb = (t & 1) ? H1 : H0;
      if (same) {
        // FAST: volatile (sc0) loads bypass L1, probe the shared L2 (v9-proven)
        const volatile bf16x8* Hv = (const volatile bf16x8*)Hb;
#pragma unroll
        for (int rt = 0; rt < 2; ++rt)
#pragma unroll
          for (int kt = 0; kt < 8; ++kt)
            afrag[rt][kt] = Hv[((size_t)(r0 + rt * 16 + cl) * 256 + kt * 32 + q * 8) >> 3];
      } else {
        // SLOW (v7-proven): plain loads post-inv.
#pragma unroll
        for (int rt = 0; rt < 2; ++rt)
#pragma unroll
          for (int kt = 0; kt < 8; ++kt)
            afrag[rt][kt] = *(const bf16x8*)(Hb + (size_t)(r0 + rt * 16 + cl) * 256 + kt * 32 + q * 8);
      }
    } else {
      // t = 0: h_0 = 0 -> no read, no wait (Hbuf may be uninitialized).
#pragma unroll
      for (int rt = 0; rt < 2; ++rt)
#pragma unroll
        for (int kt = 0; kt < 8; ++kt)
          afrag[rt][kt] = (bf16x8){0, 0, 0, 0, 0, 0, 0, 0};
    }

    // ---- MFMA: 2 row-tiles x 2 n-tiles ({i,f},{g,o} x 8 cols) x 8 k-tiles
    f32x4 acc[2][2];
#pragma unroll
    for (int rt = 0; rt < 2; ++rt)
#pragma unroll
      for (int nt = 0; nt < 2; ++nt) acc[rt][nt] = f32x4{0.f, 0.f, 0.f, 0.f};
#pragma unroll
    for (int kt = 0; kt < 8; ++kt)
#pragma unroll
      for (int rt = 0; rt < 2; ++rt)
#pragma unroll
        for (int nt = 0; nt < 2; ++nt)
          acc[rt][nt] = __builtin_amdgcn_mfma_f32_16x16x32_bf16(
              afrag[rt][kt], wlds[w][nt][kt][lane], acc[rt][nt], 0, 0, 0);

    // ---- elementwise: lane cl holds (cl<8 ? {i,g} : {f,o}); shfl_xor(8) pairs.
    unsigned short* Hw = ((t & 1) ? H0 : H1);
    bool last = (t == STEPS - 1);
    bool lo = (cl & 8) == 0;
#pragma unroll
    for (int rt = 0; rt < 2; ++rt) {
#pragma unroll
      for (int e = 0; e < 4; ++e) {
        float own0 = acc[rt][0][e], oth0 = __shfl_xor(own0, 8, 64);
        float own1 = acc[rt][1][e], oth1 = __shfl_xor(own1, 8, 64);
        float pi = (lo ? own0 : oth0) + bf2f((unsigned short)pv[rt][0][e]);
        float pf = (lo ? oth0 : own0) + bf2f((unsigned short)pv[rt][1][e]);
        float pg = (lo ? own1 : oth1) + bf2f((unsigned short)pv[rt][2][e]);
        float po = (lo ? oth1 : own1) + bf2f((unsigned short)pv[rt][3][e]);
        float ig = sig_f(pi), fg = sig_f(pf), gg = tanh_f(pg), og = sig_f(po);
        float cn = fg * creg[rt][e] + ig * gg;
        creg[rt][e] = cn;
        float hn = og * tanh_f(cn);
        int r = r0 + rt * 16 + q * 4 + e;
        if (lo) {
          if (!last) {
            Hw[(size_t)r * 256 + jglob] = f2bf(hn);  // plain store -> shared L2
          } else {
            out[(size_t)r * 256 + jglob] = hn;
            out[65536 + (size_t)r * 256 + jglob] = cn;
          }
        }
      }
    }

    if (!last) {
      // All waves' h stores are vmcnt-drained into the shared L2 by this
      // barrier; the flag store then commits to the SAME L2 (no channel race).
      __syncthreads();
      if (tid == 0) {
        if (same)
          __hip_atomic_store(frg + cg, t + 1,
                             __ATOMIC_RELAXED, __HIP_MEMORY_SCOPE_AGENT);
        else
          // SLOW (v7-proven): RELEASE = wbl2 publishes L2-dirty h to IC first
          __hip_atomic_store(frg + cg, t + 1,
                             __ATOMIC_RELEASE, __HIP_MEMORY_SCOPE_SYSTEM);
      }
    }
  }
}

extern "C" void kernel_launch(void* const* d_in, const int* in_sizes, int n_in,
                              void* d_out, int out_size, void* d_ws, size_t ws_size,
                              hipStream_t stream) {
  const float* x = (const float*)d_in[0];
  const float* wx0 = (const float*)d_in[1];
  const float* wx1 = (const float*)d_in[5];
  const float* wx2 = (const float*)d_in[9];
  const float* wx3 = (const float*)d_in[13];
  const float* wh0 = (const float*)d_in[3];
  const float* wh1 = (const float*)d_in[7];
  const float* wh2 = (const float*)d_in[11];
  const float* wh3 = (const float*)d_in[15];
  const float* bx0 = (const float*)d_in[2];
  const float* bx1 = (const float*)d_in[6];
  const float* bx2 = (const float*)d_in[10];
  const float* bx3 = (const float*)d_in[14];
  const float* bh0 = (const float*)d_in[4];
  const float* bh1 = (const float*)d_in[8];
  const float* bh2 = (const float*)d_in[12];
  const float* bh3 = (const float*)d_in[16];

  char* ws = (char*)d_ws;
  unsigned short* WxT = (unsigned short*)(ws + 0);          // dead after precompute
  unsigned short* WhT = (unsigned short*)(ws + 524288);
  float* bcat = (float*)(ws + 1048576);
  unsigned short* P = (unsigned short*)(ws + 1052672);      // [t][rg16][n][16] bf16
  int* flags = (int*)(ws + 0);                              // int[8][64], 256-B/rg
  int* xcd_tab = (int*)(ws + 8192);                         // 64 ints
  unsigned short* Hbuf = (unsigned short*)(ws + 16384);     // [2][256][256] bf16

  lstm_prep_w<<<dim3(8, 8, 8), 256, 0, stream>>>(wx0, wx1, wx2, wx3,
                                                 wh0, wh1, wh2, wh3, WxT, WhT);
  lstm_prep_b<<<4, 256, 0, stream>>>(bx0, bx1, bx2, bx3, bh0, bh1, bh2, bh3, bcat);
  lstm_precompute<<<dim3(255, 2), 256, 0, stream>>>(x, WxT, bcat, P);
  hipMemsetAsync(ws, 0, 16384, stream);  // flags + xcd_tab (Hbuf never pre-read)
  lstm_recurrent<<<dim3(8, 8), 256, 0, stream>>>(WhT, P, Hbuf, flags, xcd_tab,
                                                 (float*)d_out);
}